// Round 17
// baseline (54.889 us; speedup 1.0000x reference)
//
#include <hip/hip_runtime.h>
#include <math.h>

#define BB 4
#define SS 256
#define DD 768
#define DEPC 100
#define HH 12

typedef short bf16x8 __attribute__((ext_vector_type(8)));
typedef float f32x4 __attribute__((ext_vector_type(4)));

__device__ __forceinline__ unsigned short f2bf(float x) {
    unsigned int u = __float_as_uint(x);
    u += 0x7FFF + ((u >> 16) & 1);
    return (unsigned short)(u >> 16);
}
__device__ __forceinline__ float bf2f(unsigned short h) {
    return __uint_as_float(((unsigned int)h) << 16);
}

// ---------- K_prep: block 0 = u compute+pack; blocks 1..288 = W_v pack ----------
__global__ __launch_bounds__(256) void k_prep(const float* __restrict__ W_e,
                                              const float* __restrict__ w_rel,
                                              const float* __restrict__ W_v,
                                              unsigned short* __restrict__ upk,
                                              unsigned short* __restrict__ wpk) {
    int t = threadIdx.x;
    if (blockIdx.x == 0) {
        __shared__ float u_l[HH][DEPC];
        const float4* wr = (const float4*)w_rel;
        float4 wrv[16];
#pragma unroll
        for (int c = 0; c < 16; ++c) wrv[c] = wr[c];
        for (int e = t; e < DEPC * HH; e += 256) {
            int p = e / HH, h = e % HH;
            const float4* we = (const float4*)(W_e + p * DD + h * 64);
            float acc = 0.f;
#pragma unroll
            for (int c = 0; c < 16; ++c) {
                float4 a = we[c], b = wrv[c];
                acc += a.x * b.x + a.y * b.y + a.z * b.z + a.w * b.w;
            }
            u_l[h][p] = acc;
        }
        __syncthreads();
        int s = t >> 6, l = t & 63;
        int h = l & 15, kg = l >> 4;
        unsigned short hi[8], lo[8];
#pragma unroll
        for (int e = 0; e < 8; ++e) {
            int k = 32 * s + kg * 8 + e;
            float v = (h < HH && k < DEPC) ? u_l[h][k] : 0.f;
            unsigned short hb = f2bf(v);
            hi[e] = hb;
            lo[e] = f2bf(v - bf2f(hb));
        }
        unsigned short* dh = upk + (s * 64 + l) * 8;
        unsigned short* dl = upk + 2048 + (s * 64 + l) * 8;
#pragma unroll
        for (int e = 0; e < 8; ++e) { dh[e] = hi[e]; dl[e] = lo[e]; }
    } else {
        int unit = (blockIdx.x - 1) * 4 + (t >> 6);
        int lane = t & 63;
        int s = unit / 48, ct = unit % 48;
        int cl = lane & 15, kg = lane >> 4;
        unsigned short hi[8], lo[8];
#pragma unroll
        for (int e = 0; e < 8; ++e) {
            int k = s * 32 + kg * 8 + e;
            float v = W_v[(size_t)k * DD + ct * 16 + cl];
            unsigned short hb = f2bf(v);
            hi[e] = hb;
            lo[e] = f2bf(v - bf2f(hb));
        }
        size_t base = ((size_t)(s * 48 + ct) * 64 + lane) * 8;
        unsigned short* dh = wpk + base;
        unsigned short* dl = wpk + 589824 + base;
#pragma unroll
        for (int e = 0; e < 8; ++e) { dh[e] = hi[e]; dl[e] = lo[e]; }
    }
}

// ---------- device body: V = token @ W_v via MFMA (split-bf16) -> bf16 ----------
__device__ __forceinline__ void body_v(char* smem, int unit, int t,
                                       const float* __restrict__ A,
                                       const unsigned short* __restrict__ wpk,
                                       unsigned short* __restrict__ Vbf) {
    unsigned short* Ah = (unsigned short*)smem;
    unsigned short* Al = Ah + 2560;
#define AH(bf, r, c) Ah[((bf) * 32 + (r)) * 40 + (c)]
#define AL(bf, r, c) Al[((bf) * 32 + (r)) * 40 + (c)]
    int lane = t & 63, w = t >> 6;
    int wr = w >> 1, wc = w & 1;
    int vr = unit & 31, c0y = unit >> 5;
    int r0 = vr * 32;
    int srow = t >> 3, sq = t & 7;

    {
        float4 av = *(const float4*)&A[(size_t)(r0 + srow) * DD + 4 * sq];
        const float* af = (const float*)&av;
#pragma unroll
        for (int e = 0; e < 4; ++e) {
            unsigned short hb = f2bf(af[e]);
            AH(0, srow, 4 * sq + e) = hb;
            AL(0, srow, 4 * sq + e) = f2bf(af[e] - bf2f(hb));
        }
    }
    __syncthreads();

    int ct = c0y * 2 + wc;
    int fr = wr * 16 + (lane & 15);
    int kg = lane >> 4;
    f32x4 acc = {0.f, 0.f, 0.f, 0.f};

    for (int s = 0; s < 24; ++s) {
        float4 nx = {0, 0, 0, 0};
        if (s + 1 < 24)
            nx = *(const float4*)&A[(size_t)(r0 + srow) * DD + (s + 1) * 32 + 4 * sq];

        const unsigned short* bp = wpk + ((size_t)(s * 48 + ct) * 64 + lane) * 8;
        bf16x8 bh = *(const bf16x8*)bp;
        bf16x8 bl = *(const bf16x8*)(bp + 589824);
        bf16x8 ah = *(const bf16x8*)&AH(s & 1, fr, kg * 8);
        bf16x8 al = *(const bf16x8*)&AL(s & 1, fr, kg * 8);
        acc = __builtin_amdgcn_mfma_f32_16x16x32_bf16(ah, bh, acc, 0, 0, 0);
        acc = __builtin_amdgcn_mfma_f32_16x16x32_bf16(al, bh, acc, 0, 0, 0);
        acc = __builtin_amdgcn_mfma_f32_16x16x32_bf16(ah, bl, acc, 0, 0, 0);

        if (s + 1 < 24) {
            const float* nf = (const float*)&nx;
            int nb = (s + 1) & 1;
#pragma unroll
            for (int e = 0; e < 4; ++e) {
                unsigned short hb = f2bf(nf[e]);
                AH(nb, srow, 4 * sq + e) = hb;
                AL(nb, srow, 4 * sq + e) = f2bf(nf[e] - bf2f(hb));
            }
        }
        __syncthreads();
    }

    int col = c0y * 32 + wc * 16 + (lane & 15);
    int rowb = r0 + wr * 16 + (lane >> 4) * 4;
#pragma unroll
    for (int e = 0; e < 4; ++e)
        Vbf[(size_t)(rowb + e) * DD + col] = f2bf(acc[e]);
#undef AH
#undef AL
}

// ---------- device body: scores via MFMA — DIRECT GLOBAL LOADS, zero LDS ----------
// A-fragment loaded straight from edge: lane (arow,kg) reads 2 adjacent float4 at
// row j0+arow, bytes 128*s + 32*kg. Per s-step the wave covers 16 rows x 128 B
// contiguous (100% line use). k>=100 pad = zero frags (u-frags already zero there).
__device__ __forceinline__ void body_sc(int jc, int i, int b, int t,
                                        const float* __restrict__ edge,
                                        const int* __restrict__ mask,
                                        const unsigned short* __restrict__ upk,
                                        float* __restrict__ scores) {
    int lane = t & 63, w = t >> 6;
    int arow = lane & 15, kg = lane >> 4;
    int j0 = jc * 64 + w * 16;
    const float* rbase = edge + (size_t)((b * SS + i) * SS + j0 + arow) * DEPC + kg * 8;

    // issue all global loads up front; compiler pipelines against counted vmcnt
    float4 va[4], vb[4];
#pragma unroll
    for (int s = 0; s < 3; ++s) {
        va[s] = *(const float4*)(rbase + 32 * s);
        vb[s] = *(const float4*)(rbase + 32 * s + 4);
    }
    va[3] = (kg == 0) ? *(const float4*)(rbase + 96)   // k=96..99, in-bounds
                      : make_float4(0.f, 0.f, 0.f, 0.f);
    vb[3] = make_float4(0.f, 0.f, 0.f, 0.f);           // k>=100: pad

    bf16x8 uh[4], ul[4];
#pragma unroll
    for (int s = 0; s < 4; ++s) {
        uh[s] = *(const bf16x8*)(upk + (s * 64 + lane) * 8);
        ul[s] = *(const bf16x8*)(upk + 2048 + (s * 64 + lane) * 8);
    }

    int4 mk = *(const int4*)(mask + (size_t)(b * SS + i) * SS + j0 + kg * 4);

    f32x4 acc = {0.f, 0.f, 0.f, 0.f};
#pragma unroll
    for (int s = 0; s < 4; ++s) {
        float ev[8] = {va[s].x, va[s].y, va[s].z, va[s].w,
                       vb[s].x, vb[s].y, vb[s].z, vb[s].w};
        bf16x8 ehi, elo;
#pragma unroll
        for (int e = 0; e < 8; ++e) {
            unsigned short hb = f2bf(ev[e]);
            ehi[e] = (short)hb;
            elo[e] = (short)f2bf(ev[e] - bf2f(hb));
        }
        acc = __builtin_amdgcn_mfma_f32_16x16x32_bf16(ehi, uh[s], acc, 0, 0, 0);
        acc = __builtin_amdgcn_mfma_f32_16x16x32_bf16(ehi, ul[s], acc, 0, 0, 0);
        acc = __builtin_amdgcn_mfma_f32_16x16x32_bf16(elo, uh[s], acc, 0, 0, 0);
    }

    int h = lane & 15;
    int js = j0 + kg * 4;
    float4 r;
    r.x = mk.x ? fmaxf(acc[0], 0.f) : -1e6f;
    r.y = mk.y ? fmaxf(acc[1], 0.f) : -1e6f;
    r.z = mk.z ? fmaxf(acc[2], 0.f) : -1e6f;
    r.w = mk.w ? fmaxf(acc[3], 0.f) : -1e6f;
    if (h < HH)
        *(float4*)&scores[(((size_t)b * HH + h) * SS + i) * SS + js] = r;
}

// ---------- K_main: fused dispatch — k_v blocks (x<192) + k_sc blocks ----------
__global__ __launch_bounds__(256) void k_main(const float* __restrict__ token,
                                              const unsigned short* __restrict__ wpk,
                                              unsigned short* __restrict__ Vbf,
                                              const float* __restrict__ edge,
                                              const int* __restrict__ mask,
                                              const unsigned short* __restrict__ upk,
                                              float* __restrict__ scores) {
    __shared__ __align__(16) char smem[10240];
    int t = threadIdx.x;
    int x = blockIdx.x, b = blockIdx.y;
    if (x < 192) {
        int unit = b * 192 + x;
        body_v(smem, unit, t, token, wpk, Vbf);
    } else {
        int xx = x - 192;
        body_sc(xx & 3, xx >> 2, b, t, edge, mask, upk, scores);
    }
}

// ---------- K4: softmax + PV via MFMA.  Block = (i-tile16, h, b) ----------
__global__ __launch_bounds__(256) void k_ctx(const float* __restrict__ scores,
                                             const unsigned short* __restrict__ Vbf,
                                             const float* __restrict__ token,
                                             float* __restrict__ out) {
    __shared__ float P[16][260];
    __shared__ unsigned short Pb[16][264];
    int t = threadIdx.x;
    int i0 = blockIdx.x * 16, h = blockIdx.y, b = blockIdx.z;
    int lane = t & 63, w = t >> 6;

    const float* sbase = scores + (((size_t)b * HH + h) * SS + i0) * SS;
#pragma unroll
    for (int k = 0; k < 4; ++k) {
        int idx = t + 256 * k;
        int r = idx >> 6, jc = idx & 63;
        float4 v = *(const float4*)(sbase + (size_t)r * SS + 4 * jc);
        *(float4*)&P[r][4 * jc] = v;
    }
    __syncthreads();

    for (int r = w; r < 16; r += 4) {
        float x0 = P[r][lane],       x1 = P[r][lane + 64];
        float x2 = P[r][lane + 128], x3 = P[r][lane + 192];
        float m = fmaxf(fmaxf(x0, x1), fmaxf(x2, x3));
#pragma unroll
        for (int o = 32; o > 0; o >>= 1) m = fmaxf(m, __shfl_xor(m, o, 64));
        x0 = __expf(x0 - m); x1 = __expf(x1 - m);
        x2 = __expf(x2 - m); x3 = __expf(x3 - m);
        float s = x0 + x1 + x2 + x3;
#pragma unroll
        for (int o = 32; o > 0; o >>= 1) s += __shfl_xor(s, o, 64);
        float inv = 1.0f / s;
        Pb[r][lane]       = f2bf(x0 * inv);
        Pb[r][lane + 64]  = f2bf(x1 * inv);
        Pb[r][lane + 128] = f2bf(x2 * inv);
        Pb[r][lane + 192] = f2bf(x3 * inv);
    }
    __syncthreads();

    int cl = lane & 15, kg = lane >> 4;
    f32x4 acc = {0.f, 0.f, 0.f, 0.f};
    const unsigned short* vb = Vbf + (size_t)b * SS * DD + h * 64 + w * 16 + cl;
#pragma unroll
    for (int s = 0; s < 8; ++s) {
        bf16x8 af = *(const bf16x8*)&Pb[cl][s * 32 + kg * 8];
        bf16x8 bfr;
#pragma unroll
        for (int e = 0; e < 8; ++e)
            bfr[e] = (short)vb[(size_t)(s * 32 + kg * 8 + e) * DD];
        acc = __builtin_amdgcn_mfma_f32_16x16x32_bf16(af, bfr, acc, 0, 0, 0);
    }

    int col = h * 64 + w * 16 + cl;
#pragma unroll
    for (int e = 0; e < 4; ++e) {
        size_t o = (size_t)(b * SS + i0 + kg * 4 + e) * DD + col;
        out[o] = fmaxf(token[o] + acc[e], 0.f);
    }
}

extern "C" void kernel_launch(void* const* d_in, const int* in_sizes, int n_in,
                              void* d_out, int out_size, void* d_ws, size_t ws_size,
                              hipStream_t stream) {
    const float* token = (const float*)d_in[0];
    const float* edge  = (const float*)d_in[1];
    const int*   mask  = (const int*)d_in[2];
    const float* W_v   = (const float*)d_in[3];
    const float* W_e   = (const float*)d_in[4];
    const float* w_rel = (const float*)d_in[5];
    float* out = (float*)d_out;

    char* ws = (char*)d_ws;
    unsigned short* upk = (unsigned short*)(ws);              // 8 KB
    unsigned short* wpk = (unsigned short*)(ws + 8192);       // 2.36 MB
    unsigned short* Vbf = (unsigned short*)(ws + 8192 + 2359296);  // 1.57 MB
    float* scores = (float*)(ws + 8192 + 2359296 + 1572864 + 1024);

    hipLaunchKernelGGL(k_prep, dim3(289),              dim3(256), 0, stream, W_e, w_rel, W_v, upk, wpk);
    hipLaunchKernelGGL(k_main, dim3(192 + SS * 4, BB), dim3(256), 0, stream,
                       token, wpk, Vbf, edge, mask, upk, scores);
    hipLaunchKernelGGL(k_ctx,  dim3(16, HH, BB),       dim3(256), 0, stream, scores, Vbf, token, out);
}

// Round 18
// 52.346 us; speedup vs baseline: 1.0486x; 1.0486x over previous
//
#include <hip/hip_runtime.h>
#include <math.h>

#define BB 4
#define SS 256
#define DD 768
#define DEPC 100
#define HH 12

typedef short bf16x8 __attribute__((ext_vector_type(8)));
typedef float f32x4 __attribute__((ext_vector_type(4)));

__device__ __forceinline__ unsigned short f2bf(float x) {
    unsigned int u = __float_as_uint(x);
    u += 0x7FFF + ((u >> 16) & 1);
    return (unsigned short)(u >> 16);
}
__device__ __forceinline__ float bf2f(unsigned short h) {
    return __uint_as_float(((unsigned int)h) << 16);
}

// ---------- K_prep: block 0 = u compute+pack; blocks 1..288 = W_v pack ----------
__global__ __launch_bounds__(256) void k_prep(const float* __restrict__ W_e,
                                              const float* __restrict__ w_rel,
                                              const float* __restrict__ W_v,
                                              unsigned short* __restrict__ upk,
                                              unsigned short* __restrict__ wpk) {
    int t = threadIdx.x;
    if (blockIdx.x == 0) {
        __shared__ float u_l[HH][DEPC];
        const float4* wr = (const float4*)w_rel;
        float4 wrv[16];
#pragma unroll
        for (int c = 0; c < 16; ++c) wrv[c] = wr[c];
        for (int e = t; e < DEPC * HH; e += 256) {
            int p = e / HH, h = e % HH;
            const float4* we = (const float4*)(W_e + p * DD + h * 64);
            float acc = 0.f;
#pragma unroll
            for (int c = 0; c < 16; ++c) {
                float4 a = we[c], b = wrv[c];
                acc += a.x * b.x + a.y * b.y + a.z * b.z + a.w * b.w;
            }
            u_l[h][p] = acc;
        }
        __syncthreads();
        int s = t >> 6, l = t & 63;
        int h = l & 15, kg = l >> 4;
        unsigned short hi[8], lo[8];
#pragma unroll
        for (int e = 0; e < 8; ++e) {
            int k = 32 * s + kg * 8 + e;
            float v = (h < HH && k < DEPC) ? u_l[h][k] : 0.f;
            unsigned short hb = f2bf(v);
            hi[e] = hb;
            lo[e] = f2bf(v - bf2f(hb));
        }
        unsigned short* dh = upk + (s * 64 + l) * 8;
        unsigned short* dl = upk + 2048 + (s * 64 + l) * 8;
#pragma unroll
        for (int e = 0; e < 8; ++e) { dh[e] = hi[e]; dl[e] = lo[e]; }
    } else {
        int unit = (blockIdx.x - 1) * 4 + (t >> 6);
        int lane = t & 63;
        int s = unit / 48, ct = unit % 48;
        int cl = lane & 15, kg = lane >> 4;
        unsigned short hi[8], lo[8];
#pragma unroll
        for (int e = 0; e < 8; ++e) {
            int k = s * 32 + kg * 8 + e;
            float v = W_v[(size_t)k * DD + ct * 16 + cl];
            unsigned short hb = f2bf(v);
            hi[e] = hb;
            lo[e] = f2bf(v - bf2f(hb));
        }
        size_t base = ((size_t)(s * 48 + ct) * 64 + lane) * 8;
        unsigned short* dh = wpk + base;
        unsigned short* dl = wpk + 589824 + base;
#pragma unroll
        for (int e = 0; e < 8; ++e) { dh[e] = hi[e]; dl[e] = lo[e]; }
    }
}

// ---------- device body: V = token @ W_v via MFMA (split-bf16) -> bf16 ----------
__device__ __forceinline__ void body_v(char* smem, int unit, int t,
                                       const float* __restrict__ A,
                                       const unsigned short* __restrict__ wpk,
                                       unsigned short* __restrict__ Vbf) {
    unsigned short* Ah = (unsigned short*)smem;
    unsigned short* Al = Ah + 2560;
#define AH(bf, r, c) Ah[((bf) * 32 + (r)) * 40 + (c)]
#define AL(bf, r, c) Al[((bf) * 32 + (r)) * 40 + (c)]
    int lane = t & 63, w = t >> 6;
    int wr = w >> 1, wc = w & 1;
    int vr = unit & 31, c0y = unit >> 5;
    int r0 = vr * 32;
    int srow = t >> 3, sq = t & 7;

    {
        float4 av = *(const float4*)&A[(size_t)(r0 + srow) * DD + 4 * sq];
        const float* af = (const float*)&av;
#pragma unroll
        for (int e = 0; e < 4; ++e) {
            unsigned short hb = f2bf(af[e]);
            AH(0, srow, 4 * sq + e) = hb;
            AL(0, srow, 4 * sq + e) = f2bf(af[e] - bf2f(hb));
        }
    }
    __syncthreads();

    int ct = c0y * 2 + wc;
    int fr = wr * 16 + (lane & 15);
    int kg = lane >> 4;
    f32x4 acc = {0.f, 0.f, 0.f, 0.f};

    for (int s = 0; s < 24; ++s) {
        float4 nx = {0, 0, 0, 0};
        if (s + 1 < 24)
            nx = *(const float4*)&A[(size_t)(r0 + srow) * DD + (s + 1) * 32 + 4 * sq];

        const unsigned short* bp = wpk + ((size_t)(s * 48 + ct) * 64 + lane) * 8;
        bf16x8 bh = *(const bf16x8*)bp;
        bf16x8 bl = *(const bf16x8*)(bp + 589824);
        bf16x8 ah = *(const bf16x8*)&AH(s & 1, fr, kg * 8);
        bf16x8 al = *(const bf16x8*)&AL(s & 1, fr, kg * 8);
        acc = __builtin_amdgcn_mfma_f32_16x16x32_bf16(ah, bh, acc, 0, 0, 0);
        acc = __builtin_amdgcn_mfma_f32_16x16x32_bf16(al, bh, acc, 0, 0, 0);
        acc = __builtin_amdgcn_mfma_f32_16x16x32_bf16(ah, bl, acc, 0, 0, 0);

        if (s + 1 < 24) {
            const float* nf = (const float*)&nx;
            int nb = (s + 1) & 1;
#pragma unroll
            for (int e = 0; e < 4; ++e) {
                unsigned short hb = f2bf(nf[e]);
                AH(nb, srow, 4 * sq + e) = hb;
                AL(nb, srow, 4 * sq + e) = f2bf(nf[e] - bf2f(hb));
            }
        }
        __syncthreads();
    }

    int col = c0y * 32 + wc * 16 + (lane & 15);
    int rowb = r0 + wr * 16 + (lane >> 4) * 4;
#pragma unroll
    for (int e = 0; e < 4; ++e)
        Vbf[(size_t)(rowb + e) * DD + col] = f2bf(acc[e]);
#undef AH
#undef AL
}

// ---------- device body: scores (MFMA, direct global) + in-block softmax -> bf16 probs ----------
// Block = (b, i), all 256 j. 4 waves x 4 tiles; scores stay in LDS; probs bf16 to global.
__device__ __forceinline__ void body_sc(char* smem, int i, int b, int t,
                                        const float* __restrict__ edge,
                                        const int* __restrict__ mask,
                                        const unsigned short* __restrict__ upk,
                                        unsigned short* __restrict__ Pbg) {
    float (*sc)[260] = (float(*)[260])smem;  // [12][260] fp32, 12.5 KB
    int lane = t & 63, w = t >> 6;
    int arow = lane & 15, kg = lane >> 4;

    bf16x8 uh[4], ul[4];
#pragma unroll
    for (int s = 0; s < 4; ++s) {
        uh[s] = *(const bf16x8*)(upk + (s * 64 + lane) * 8);
        ul[s] = *(const bf16x8*)(upk + 2048 + (s * 64 + lane) * 8);
    }

#pragma unroll
    for (int c = 0; c < 4; ++c) {
        int j0 = (w * 4 + c) * 16;
        const float* rbase = edge + (size_t)((b * SS + i) * SS + j0 + arow) * DEPC + kg * 8;
        float4 va[4], vb[4];
#pragma unroll
        for (int s = 0; s < 3; ++s) {
            va[s] = *(const float4*)(rbase + 32 * s);
            vb[s] = *(const float4*)(rbase + 32 * s + 4);
        }
        va[3] = (kg == 0) ? *(const float4*)(rbase + 96)
                          : make_float4(0.f, 0.f, 0.f, 0.f);
        vb[3] = make_float4(0.f, 0.f, 0.f, 0.f);

        int4 mk = *(const int4*)(mask + (size_t)(b * SS + i) * SS + j0 + kg * 4);

        f32x4 acc = {0.f, 0.f, 0.f, 0.f};
#pragma unroll
        for (int s = 0; s < 4; ++s) {
            float ev[8] = {va[s].x, va[s].y, va[s].z, va[s].w,
                           vb[s].x, vb[s].y, vb[s].z, vb[s].w};
            bf16x8 ehi, elo;
#pragma unroll
            for (int e = 0; e < 8; ++e) {
                unsigned short hb = f2bf(ev[e]);
                ehi[e] = (short)hb;
                elo[e] = (short)f2bf(ev[e] - bf2f(hb));
            }
            acc = __builtin_amdgcn_mfma_f32_16x16x32_bf16(ehi, uh[s], acc, 0, 0, 0);
            acc = __builtin_amdgcn_mfma_f32_16x16x32_bf16(ehi, ul[s], acc, 0, 0, 0);
            acc = __builtin_amdgcn_mfma_f32_16x16x32_bf16(elo, uh[s], acc, 0, 0, 0);
        }

        int h = lane & 15;
        if (h < HH) {
            int jj = j0 + kg * 4;
            sc[h][jj]     = mk.x ? fmaxf(acc[0], 0.f) : -1e6f;
            sc[h][jj + 1] = mk.y ? fmaxf(acc[1], 0.f) : -1e6f;
            sc[h][jj + 2] = mk.z ? fmaxf(acc[2], 0.f) : -1e6f;
            sc[h][jj + 3] = mk.w ? fmaxf(acc[3], 0.f) : -1e6f;
        }
    }
    __syncthreads();

    // softmax: wave w owns head rows w*3 .. w*3+2; probs -> global bf16
#pragma unroll
    for (int r = w * 3; r < w * 3 + 3; ++r) {
        float x0 = sc[r][lane],       x1 = sc[r][lane + 64];
        float x2 = sc[r][lane + 128], x3 = sc[r][lane + 192];
        float m = fmaxf(fmaxf(x0, x1), fmaxf(x2, x3));
#pragma unroll
        for (int o = 32; o > 0; o >>= 1) m = fmaxf(m, __shfl_xor(m, o, 64));
        x0 = __expf(x0 - m); x1 = __expf(x1 - m);
        x2 = __expf(x2 - m); x3 = __expf(x3 - m);
        float s = x0 + x1 + x2 + x3;
#pragma unroll
        for (int o = 32; o > 0; o >>= 1) s += __shfl_xor(s, o, 64);
        float inv = 1.0f / s;
        unsigned short* pb = Pbg + (((size_t)(b * HH + r) * SS + i) * SS);
        pb[lane]       = f2bf(x0 * inv);
        pb[lane + 64]  = f2bf(x1 * inv);
        pb[lane + 128] = f2bf(x2 * inv);
        pb[lane + 192] = f2bf(x3 * inv);
    }
}

// ---------- K_main: fused dispatch — k_v blocks (x<192) + sc+softmax blocks ----------
__global__ __launch_bounds__(256) void k_main(const float* __restrict__ token,
                                              const unsigned short* __restrict__ wpk,
                                              unsigned short* __restrict__ Vbf,
                                              const float* __restrict__ edge,
                                              const int* __restrict__ mask,
                                              const unsigned short* __restrict__ upk,
                                              unsigned short* __restrict__ Pbg) {
    __shared__ __align__(16) char smem[12480];
    int t = threadIdx.x;
    int x = blockIdx.x, b = blockIdx.y;
    if (x < 192) {
        int unit = b * 192 + x;
        body_v(smem, unit, t, token, wpk, Vbf);
    } else {
        body_sc(smem, x - 192, b, t, edge, mask, upk, Pbg);
    }
}

// ---------- K_ctx2: pure PV via MFMA; probs read as A-fragments from global ----------
__global__ __launch_bounds__(256) void k_ctx2(const unsigned short* __restrict__ Pbg,
                                              const unsigned short* __restrict__ Vbf,
                                              const float* __restrict__ token,
                                              float* __restrict__ out) {
    int t = threadIdx.x;
    int i0 = blockIdx.x * 16, h = blockIdx.y, b = blockIdx.z;
    int lane = t & 63, w = t >> 6;
    int arow = lane & 15, kg = lane >> 4;

    const unsigned short* prow = Pbg + ((size_t)(b * HH + h) * SS + i0 + arow) * SS;
    const unsigned short* vb = Vbf + (size_t)b * SS * DD + h * 64 + w * 16 + arow;

    f32x4 acc = {0.f, 0.f, 0.f, 0.f};
#pragma unroll
    for (int s = 0; s < 8; ++s) {
        bf16x8 af = *(const bf16x8*)(prow + s * 32 + kg * 8);
        bf16x8 bfr;
#pragma unroll
        for (int e = 0; e < 8; ++e)
            bfr[e] = (short)vb[(size_t)(s * 32 + kg * 8 + e) * DD];
        acc = __builtin_amdgcn_mfma_f32_16x16x32_bf16(af, bfr, acc, 0, 0, 0);
    }

    int col = h * 64 + w * 16 + arow;
#pragma unroll
    for (int e = 0; e < 4; ++e) {
        size_t o = (size_t)(b * SS + i0 + kg * 4 + e) * DD + col;
        out[o] = fmaxf(token[o] + acc[e], 0.f);
    }
}

extern "C" void kernel_launch(void* const* d_in, const int* in_sizes, int n_in,
                              void* d_out, int out_size, void* d_ws, size_t ws_size,
                              hipStream_t stream) {
    const float* token = (const float*)d_in[0];
    const float* edge  = (const float*)d_in[1];
    const int*   mask  = (const int*)d_in[2];
    const float* W_v   = (const float*)d_in[3];
    const float* W_e   = (const float*)d_in[4];
    const float* w_rel = (const float*)d_in[5];
    float* out = (float*)d_out;

    char* ws = (char*)d_ws;
    unsigned short* upk = (unsigned short*)(ws);                   // 8 KB
    unsigned short* wpk = (unsigned short*)(ws + 8192);            // 2.36 MB
    unsigned short* Vbf = (unsigned short*)(ws + 8192 + 2359296);  // 1.57 MB
    unsigned short* Pbg = (unsigned short*)(ws + 8192 + 2359296 + 1572864);  // 6.3 MB

    hipLaunchKernelGGL(k_prep, dim3(289),           dim3(256), 0, stream, W_e, w_rel, W_v, upk, wpk);
    hipLaunchKernelGGL(k_main, dim3(192 + SS, BB),  dim3(256), 0, stream,
                       token, wpk, Vbf, edge, mask, upk, Pbg);
    hipLaunchKernelGGL(k_ctx2, dim3(16, HH, BB),    dim3(256), 0, stream, Pbg, Vbf, token, out);
}